// Round 7
// baseline (170.644 us; speedup 1.0000x reference)
//
#include <hip/hip_runtime.h>
#include <hip/hip_bf16.h>

typedef float f32x4 __attribute__((ext_vector_type(4)));

#define SD 8192      // S*D
#define NROWS 8192   // B*N
#define NN 4096      // N
#define DD 2048      // D

// K0: Wt[k][j] = w[j][k] * (gamma[j]+1), k in 0..23 (20 alpha cols, 4 beta cols)
__global__ void k0_prep(const float* __restrict__ gamma,
                        const float* __restrict__ daf,
                        const float* __restrict__ dbf,
                        float* __restrict__ Wt) {
    int idx = blockIdx.x * 256 + threadIdx.x;
    if (idx >= 24 * SD) return;
    int k = idx >> 13;          // /8192
    int j = idx & (SD - 1);
    float g = gamma[j] + 1.0f;
    float w = (k < 20) ? daf[j * 20 + k] : dbf[j * 4 + (k - 20)];
    Wt[(size_t)k * SD + j] = w * g;
}

// K1: per-row reductions via async global->LDS staging with COUNTED vmcnt.
// Per-lane tile widened to ALL 25 k (lane = jq in 0..63 owns quad lane*4 of
// each 256-float chunk; wave owns 4 rows): 28 ds_read_b128 per chunk per lane
// for 1600 FMAs (vs 40 before) -> LDS-pipe time below the HBM floor.
// Block = 256 thr, 16 rows, 32 chunks, double-buffered LDS (80 KiB, 2 blk/CU).
// Stage: wave issues 10 global_load_lds per chunk (4 data rows + 6 weight rows);
// vmcnt(10) at the barrier keeps the next chunk's 10 in flight (T4).
__global__ __launch_bounds__(256) void k1_reduce(const float* __restrict__ res,
                                                 const float* __restrict__ Wt,
                                                 float* __restrict__ RS) {
    __shared__ float lds[2][10240];     // [buf][0..4095]=data, [4096..10239]=weights
    const int tid  = threadIdx.x;
    const int wv   = tid >> 6;
    const int lane = tid & 63;
    const int row0 = blockIdx.x * 16;
    const int b    = row0 >> 12;
    const int n0   = row0 & (NN - 1);

    float acc[4][24];
    float ssq[4];
#pragma unroll
    for (int i = 0; i < 4; ++i) {
        ssq[i] = 0.f;
#pragma unroll
        for (int k = 0; k < 24; ++k) acc[i][k] = 0.f;
    }

    auto stage = [&](int buf, int c) {
        const int s = c >> 3;
        const int dbase = (c & 7) * 256;
#pragma unroll
        for (int i = 0; i < 4; ++i) {
            const int r = wv * 4 + i;
            const float* g = res + ((size_t)(b * 4 + s) * NN + (n0 + r)) * DD + dbase + lane * 4;
            float* l = &lds[buf][r * 256];
            __builtin_amdgcn_global_load_lds((const __attribute__((address_space(1))) void*)g,
                                             (__attribute__((address_space(3))) void*)l,
                                             16, 0, 0);
        }
#pragma unroll
        for (int kk = 0; kk < 6; ++kk) {
            const int k = wv * 6 + kk;
            const float* g = Wt + (size_t)k * SD + c * 256 + lane * 4;
            float* l = &lds[buf][4096 + k * 256];
            __builtin_amdgcn_global_load_lds((const __attribute__((address_space(1))) void*)g,
                                             (__attribute__((address_space(3))) void*)l,
                                             16, 0, 0);
        }
    };

    auto compute = [&](int buf) {
        const float* dT = &lds[buf][0];
        const float* wT = &lds[buf][4096];
        const int fq = lane * 4;
        f32x4 d[4];
#pragma unroll
        for (int i = 0; i < 4; ++i)
            d[i] = *(const f32x4*)&dT[(wv * 4 + i) * 256 + fq];
#pragma unroll
        for (int i = 0; i < 4; ++i) {
            ssq[i] += d[i].x * d[i].x;
            ssq[i] += d[i].y * d[i].y;
            ssq[i] += d[i].z * d[i].z;
            ssq[i] += d[i].w * d[i].w;
        }
#pragma unroll
        for (int k = 0; k < 24; ++k) {
            const f32x4 w = *(const f32x4*)&wT[k * 256 + fq];
#pragma unroll
            for (int i = 0; i < 4; ++i) {
                acc[i][k] += d[i].x * w.x;
                acc[i][k] += d[i].y * w.y;
                acc[i][k] += d[i].z * w.z;
                acc[i][k] += d[i].w * w.w;
            }
        }
    };

    stage(0, 0);
    stage(1, 1);
    for (int c = 0; c < 32; ++c) {
        if (c < 30) {
            // current buffer's 10 loads done; next buffer's 10 stay in flight
            asm volatile("s_waitcnt vmcnt(10)" ::: "memory");
        } else {
            asm volatile("s_waitcnt vmcnt(0)" ::: "memory");
        }
        __builtin_amdgcn_sched_barrier(0);
        __builtin_amdgcn_s_barrier();
        compute(c & 1);
        __builtin_amdgcn_s_barrier();   // all waves done reading buf before re-stage
        if (c + 2 < 32) stage(c & 1, c + 2);
    }

    // butterfly reduce across all 64 lanes
#pragma unroll
    for (int i = 0; i < 4; ++i) {
#pragma unroll
        for (int k = 0; k < 24; ++k) {
            float v = acc[i][k];
            v += __shfl_xor(v, 1);
            v += __shfl_xor(v, 2);
            v += __shfl_xor(v, 4);
            v += __shfl_xor(v, 8);
            v += __shfl_xor(v, 16);
            v += __shfl_xor(v, 32);
            acc[i][k] = v;
        }
        float v = ssq[i];
        v += __shfl_xor(v, 1);
        v += __shfl_xor(v, 2);
        v += __shfl_xor(v, 4);
        v += __shfl_xor(v, 8);
        v += __shfl_xor(v, 16);
        v += __shfl_xor(v, 32);
        ssq[i] = v;
    }
    if (lane == 0) {
#pragma unroll
        for (int i = 0; i < 4; ++i) {
            const size_t base = (size_t)(row0 + wv * 4 + i) * 32;
#pragma unroll
            for (int k = 0; k < 24; ++k) RS[base + k] = acc[i][k];
            RS[base + 24] = ssq[i];
        }
    }
}

// K2: per-row alpha/sinkhorn/beta -> Coef[row][t*4+s]. 16 lanes per row (l = s*4+t).
__global__ void k2_coef(const float* __restrict__ RS,
                        const float* __restrict__ sa,
                        const float* __restrict__ sb,
                        const float* __restrict__ pbs,
                        const float* __restrict__ rsc,
                        const float* __restrict__ hps,
                        float* __restrict__ Coef) {
    const int tid = threadIdx.x;
    const int g = tid >> 4, l = tid & 15;
    const int row = blockIdx.x * 16 + g;
    const int s = l >> 2, t = l & 3;
    const float* rr = RS + (size_t)row * 32;
    const float scale = 90.50966799187809f / fmaxf(sqrtf(rr[24]), 1e-12f); // sqrt(8192)/norm
    float la = scale * rr[s * 5 + t + 1] * rsc[0] + sa[s * 5 + t + 1];
    const float a0 = scale * rr[s * 5] * pbs[0] + sa[s * 5];
    const float ap = 1.f / (1.f + __expf(-a0));
    const float bt = 2.f / (1.f + __expf(-(scale * rr[20 + t] * hps[0] + sb[t])));
#pragma unroll
    for (int it = 0; it < 20; ++it) {
        // column LSE (over s): xor 4, 8
        float m = fmaxf(la, __shfl_xor(la, 4));
        m = fmaxf(m, __shfl_xor(m, 8));
        float e = __expf(la - m);
        e += __shfl_xor(e, 4);
        e += __shfl_xor(e, 8);
        la -= m + __logf(e);
        // row LSE (over t): xor 1, 2
        m = fmaxf(la, __shfl_xor(la, 1));
        m = fmaxf(m, __shfl_xor(m, 2));
        e = __expf(la - m);
        e += __shfl_xor(e, 1);
        e += __shfl_xor(e, 2);
        la -= m + __logf(e);
    }
    Coef[(size_t)row * 16 + t * 4 + s] = ap * bt + __expf(la);
}

// K3: out[t][d] = sum_s coeff[t][s] * r[s][d]. One block per row, reverse order
// (L3 LRU friendliness), nontemporal stores.
__global__ __launch_bounds__(256) void k3_mix(const float* __restrict__ res,
                                              const float* __restrict__ Coef,
                                              float* __restrict__ out) {
    const int row = (NROWS - 1) - blockIdx.x;
    const int b = row >> 12, n = row & (NN - 1);
    const int tid = threadIdx.x;
    float cf[16];
#pragma unroll
    for (int i = 0; i < 16; ++i) cf[i] = Coef[(size_t)row * 16 + i];
    f32x4 rv[4][2];
#pragma unroll
    for (int s = 0; s < 4; ++s)
#pragma unroll
        for (int p = 0; p < 2; ++p) {
            const size_t g = ((size_t)(b * 4 + s) * NN + n) * DD + p * 1024 + tid * 4;
            rv[s][p] = __builtin_nontemporal_load((const f32x4*)(res + g));
        }
#pragma unroll
    for (int t = 0; t < 4; ++t)
#pragma unroll
        for (int p = 0; p < 2; ++p) {
            f32x4 o = cf[t * 4 + 0] * rv[0][p];
            o += cf[t * 4 + 1] * rv[1][p];
            o += cf[t * 4 + 2] * rv[2][p];
            o += cf[t * 4 + 3] * rv[3][p];
            const size_t g = ((size_t)(b * 4 + t) * NN + n) * DD + p * 1024 + tid * 4;
            __builtin_nontemporal_store(o, (f32x4*)(out + g));
        }
}

extern "C" void kernel_launch(void* const* d_in, const int* in_sizes, int n_in,
                              void* d_out, int out_size, void* d_ws, size_t ws_size,
                              hipStream_t stream) {
    const float* residuals = (const float*)d_in[0];
    const float* gamma     = (const float*)d_in[1];
    const float* daf       = (const float*)d_in[2];
    const float* sa        = (const float*)d_in[3];
    const float* pbs       = (const float*)d_in[4];
    const float* rsc       = (const float*)d_in[5];
    const float* dbf       = (const float*)d_in[6];
    const float* sb        = (const float*)d_in[7];
    const float* hps       = (const float*)d_in[8];
    float* out = (float*)d_out;

    char* ws = (char*)d_ws;
    float* Wt   = (float*)ws;                       // 24*8192 f32 = 768 KiB
    float* RS   = (float*)(ws + (1 << 20));         // 8192*32 f32 = 1 MiB
    float* Coef = (float*)(ws + (2 << 20));         // 8192*16 f32 = 512 KiB

    k0_prep<<<768, 256, 0, stream>>>(gamma, daf, dbf, Wt);
    k1_reduce<<<512, 256, 0, stream>>>(residuals, Wt, RS);
    k2_coef<<<512, 256, 0, stream>>>(RS, sa, sb, pbs, rsc, hps, Coef);
    k3_mix<<<NROWS, 256, 0, stream>>>(residuals, Coef, out);
}